// Round 8
// baseline (174.644 us; speedup 1.0000x reference)
//
#include <hip/hip_runtime.h>
#include <hip/hip_bf16.h>

#define B_  8
#define T_  16
#define N_  1024
#define FI  32
#define FO  64
#define K_  3

typedef float  f32x4  __attribute__((ext_vector_type(4)));
typedef short  bf16x8 __attribute__((ext_vector_type(8)));
typedef unsigned int   u32x4 __attribute__((ext_vector_type(4)));

__device__ inline unsigned short f2bf(float f) {
    unsigned int u = __float_as_uint(f);
    u += 0x7fffu + ((u >> 16) & 1u);
    return (unsigned short)(u >> 16);
}

// packed fp32x2 -> bf16x2 (v_cvt_pk_bf16_f32 on gfx950)
__device__ inline unsigned int pkbf2(float a, float b) {
    __hip_bfloat162 h = __float22bfloat162_rn(make_float2(a, b));
    union { __hip_bfloat162 h2; unsigned int u; } cvt;
    cvt.h2 = h;
    return cvt.u;
}

// async 16-B global -> LDS (global_load_lds_dwordx4); LDS dest is
// wave-uniform base + lane*16 (contiguous per wave).
__device__ inline void gl_lds16(const unsigned short* g, unsigned short* l) {
    __builtin_amdgcn_global_load_lds(
        (const __attribute__((address_space(1))) unsigned int*)g,
        (__attribute__((address_space(3))) unsigned int*)l, 16, 0, 0);
}

// ---------------------------------------------------------------------------
// Kernel 1 "prep" v2: TRANSPOSE ONLY (ac eliminated — A is computed on the
// fly inside fused_gemm from att/cheb f32, bit-identically).
//   x[b,t,j,f] fp32 -> xt[b, t*32+f, j] bf16.  25 MB traffic ~= 4.5 us.
// ---------------------------------------------------------------------------
__global__ __launch_bounds__(256)
void prep(const float* __restrict__ x, unsigned short* __restrict__ xt) {
    __shared__ __align__(16) float tile[64][33];
    int task = blockIdx.x;
    int tid  = threadIdx.x;

    int jt = task & 15;
    int bt = task >> 4;
    int j0 = jt * 64;
    const float* src = x + (size_t)bt * (N_ * FI) + (size_t)j0 * FI;
    #pragma unroll
    for (int s = 0; s < 2; s++) {
        int e4 = tid + s * 256;
        int j  = e4 >> 3;
        int f4 = e4 & 7;
        f32x4 v = *(const f32x4*)(src + j * FI + f4 * 4);
        tile[j][f4 * 4 + 0] = v[0];
        tile[j][f4 * 4 + 1] = v[1];
        tile[j][f4 * 4 + 2] = v[2];
        tile[j][f4 * 4 + 3] = v[3];
    }
    __syncthreads();
    int f  = tid >> 3;
    int j8 = (tid & 7) * 8;
    u32x4 pk;
    #pragma unroll
    for (int u = 0; u < 4; u++)
        pk[u] = pkbf2(tile[j8 + 2 * u][f], tile[j8 + 2 * u + 1][f]);
    *(u32x4*)(xt + (size_t)bt * (32 * 1024) + j0 + f * 1024 + j8) = pk;
}

// ---------------------------------------------------------------------------
// Kernel 2 (fused, v8): ON-THE-FLY A.  R3/R6/R7 proved scheduling is
// exhausted (~43 us at 23% on every pipe; grid 512 caps occupancy at 2/CU).
// So: delete the ac tensor.  Each lane loads raw att(f32x8)+cheb(3xf32x8)
// for its A-slot (8 dwordx4, prefetched 1 KS ahead) and converts to bf16
// with the SAME pkbf2 rounding prep used -> bit-identical A, ~97 MB of
// prep traffic gone.  The convert's compiler-inserted vmcnt wait on
// raw(kb) automatically drains stage(kb) (issued 2 KS earlier) before the
// publish barrier; explicit vmcnt(10) is belt-and-suspenders (10 = newer
// ops stage(kb+1)2 + raw(kb+1)8).  BK=32, B staging = R3's proven 2-bit
// source swizzle.  2 barriers/KS, no lgkm drains (MFMA consumption
// retires ds_reads before the overwrite barrier).
// ---------------------------------------------------------------------------
#define TS_LD 104
#define CS_LD 104

struct RawA { f32x4 a[2]; f32x4 c[3][2]; };   // att 8 f32 + cheb 3x8 f32

__device__ inline void conv3(const RawA& R, bf16x8* aC) {
    #pragma unroll
    for (int k = 0; k < 3; k++) {
        union { u32x4 u; bf16x8 h; } pk;
        pk.u[0] = pkbf2(R.a[0][0] * R.c[k][0][0], R.a[0][1] * R.c[k][0][1]);
        pk.u[1] = pkbf2(R.a[0][2] * R.c[k][0][2], R.a[0][3] * R.c[k][0][3]);
        pk.u[2] = pkbf2(R.a[1][0] * R.c[k][1][0], R.a[1][1] * R.c[k][1][1]);
        pk.u[3] = pkbf2(R.a[1][2] * R.c[k][1][2], R.a[1][3] * R.c[k][1][3]);
        aC[k] = pk.h;
    }
}

__global__ __launch_bounds__(256, 2)
void fused_gemm(const float* __restrict__ att,
                const float* __restrict__ cheb,
                const unsigned short* __restrict__ xt,
                const float* __restrict__ theta,
                float* __restrict__ out) {
    // union: staging 2 x 4096 shorts (16 KB) under epilogue Cs
    // (4t x 64i x CS_LD = 26624 shorts = 53.2 KB).  + Ts 13.3 KB = 66.5 KB.
    __shared__ __align__(16) unsigned short ldsU[4 * 64 * CS_LD];
    __shared__ __align__(16) unsigned short Ts[FO * TS_LD];     // Theta^T

    unsigned short* Cs = ldsU;              // [4 t][64 i][CS_LD q]

    int blk  = blockIdx.x;
    int b    = blk & 7;          // XCD-aligned batch
    int slot = blk >> 3;         // 0..63
    int it   = slot >> 2;        // 0..15
    int ct   = slot & 3;         // 0..3
    int i0   = it * 64;
    int c0   = ct * 128;

    int tid  = threadIdx.x;
    int lane = tid & 63;
    int w    = tid >> 6;         // wave 0..3: owns i-rows w*16..w*16+15
    int quad = lane >> 4;
    int l15  = lane & 15;

    // stage Theta^T: Ts[o][q] = bf16(theta[q*64+o]), q = k*32+f
    #pragma unroll
    for (int s = 0; s < 24; s++) {
        int e = tid + s * 256;
        int q = e >> 6, o = e & 63;
        Ts[o * TS_LD + q] = f2bf(theta[e]);
    }

    const unsigned short* Bg = xt + (size_t)b * (512 * 1024);

    // ---- B staging addresses (2-bit source swizzle, LDS linear; R3) ----
    int sr  = tid >> 2;                               // staged row 0..63
    int scs = (((tid & 3) ^ ((sr >> 1) & 3)) * 8);    // swizzled source col
    const unsigned short* Brow  = Bg + (size_t)(c0 + sr) * N_ + scs;
    const unsigned short* BrowU = Brow + (size_t)64 * N_;
    unsigned short* S0r = ldsU;
    unsigned short* S1r = ldsU + 4096;
    unsigned short* S0w = ldsU + tid * 8;
    unsigned short* S1w = ldsU + 4096 + tid * 8;

    // read-side swizzle: global slot `quad` lives at LDS slot quad^s4
    int s4   = (l15 >> 1) & 3;
    int rdB0 = l15 * 32 + ((quad ^ s4) * 8);

    // ---- per-lane A source rows (f32) ----
    int ir = i0 + w * 16 + l15;
    const float* attR = att  + (size_t)b * (N_ * N_) + (size_t)ir * N_ + quad * 8;
    const float* chR0 = cheb + (size_t)ir * N_ + quad * 8;
    const float* chR1 = chR0 + (size_t)N_ * N_;
    const float* chR2 = chR1 + (size_t)N_ * N_;

    f32x4 acc[3][8];
    #pragma unroll
    for (int k = 0; k < 3; k++)
        #pragma unroll
        for (int nt = 0; nt < 8; nt++)
            acc[k][nt] = (f32x4){0.f, 0.f, 0.f, 0.f};

    RawA rE, rO;

#define RAWLOAD(R, j)                                                         \
    do {                                                                      \
        R.a[0]    = *(const f32x4*)(attR + (j));                              \
        R.a[1]    = *(const f32x4*)(attR + (j) + 4);                          \
        R.c[0][0] = *(const f32x4*)(chR0 + (j));                              \
        R.c[0][1] = *(const f32x4*)(chR0 + (j) + 4);                          \
        R.c[1][0] = *(const f32x4*)(chR1 + (j));                              \
        R.c[1][1] = *(const f32x4*)(chR1 + (j) + 4);                          \
        R.c[2][0] = *(const f32x4*)(chR2 + (j));                              \
        R.c[2][1] = *(const f32x4*)(chR2 + (j) + 4);                          \
    } while (0)

    // ---- prologue: stage(0), raw(0), stage(1) — queue order pinned ----
    gl_lds16(Brow,       S0w);
    gl_lds16(BrowU,      S0w + 2048);
    __builtin_amdgcn_sched_barrier(0);
    RAWLOAD(rE, 0);
    __builtin_amdgcn_sched_barrier(0);
    gl_lds16(Brow + 32,  S1w);
    gl_lds16(BrowU + 32, S1w + 2048);
    __builtin_amdgcn_sched_barrier(0);

#define KS(kb, RC, RN, SR, SW, WN)                                            \
  do {                                                                        \
    bf16x8 aC[3];                                                             \
    conv3(RC, aC);                 /* implicit vmcnt wait drains stage(kb) */ \
    if ((kb) < 31) RAWLOAD(RN, ((kb) + 1) * 32);                              \
    __builtin_amdgcn_sched_barrier(0);                                        \
    asm volatile("s_waitcnt vmcnt(" WN ")" ::: "memory");                     \
    __builtin_amdgcn_s_barrier();                                             \
    __builtin_amdgcn_sched_barrier(0);                                        \
    bf16x8 b0[8];                                                             \
    _Pragma("unroll")                                                         \
    for (int nt = 0; nt < 8; nt++)                                            \
      b0[nt] = *(const bf16x8*)((SR) + nt * 512 + rdB0);                      \
    __builtin_amdgcn_s_setprio(1);                                            \
    _Pragma("unroll")                                                         \
    for (int nt = 0; nt < 8; nt++) {                                          \
      acc[0][nt] = __builtin_amdgcn_mfma_f32_16x16x32_bf16(aC[0], b0[nt], acc[0][nt], 0, 0, 0); \
      acc[1][nt] = __builtin_amdgcn_mfma_f32_16x16x32_bf16(aC[1], b0[nt], acc[1][nt], 0, 0, 0); \
      acc[2][nt] = __builtin_amdgcn_mfma_f32_16x16x32_bf16(aC[2], b0[nt], acc[2][nt], 0, 0, 0); \
    }                                                                         \
    __builtin_amdgcn_s_setprio(0);                                            \
    __builtin_amdgcn_sched_barrier(0);                                        \
    __builtin_amdgcn_s_barrier();                                             \
    __builtin_amdgcn_sched_barrier(0);                                        \
    if ((kb) < 30) {                                                          \
      gl_lds16(Brow  + ((kb) + 2) * 32, (SW));                                \
      gl_lds16(BrowU + ((kb) + 2) * 32, (SW) + 2048);                         \
    }                                                                         \
  } while (0)

    KS(0,  rE, rO, S0r, S0w, "10");
    KS(1,  rO, rE, S1r, S1w, "10");
    KS(2,  rE, rO, S0r, S0w, "10");
    KS(3,  rO, rE, S1r, S1w, "10");
    KS(4,  rE, rO, S0r, S0w, "10");
    KS(5,  rO, rE, S1r, S1w, "10");
    KS(6,  rE, rO, S0r, S0w, "10");
    KS(7,  rO, rE, S1r, S1w, "10");
    KS(8,  rE, rO, S0r, S0w, "10");
    KS(9,  rO, rE, S1r, S1w, "10");
    KS(10, rE, rO, S0r, S0w, "10");
    KS(11, rO, rE, S1r, S1w, "10");
    KS(12, rE, rO, S0r, S0w, "10");
    KS(13, rO, rE, S1r, S1w, "10");
    KS(14, rE, rO, S0r, S0w, "10");
    KS(15, rO, rE, S1r, S1w, "10");
    KS(16, rE, rO, S0r, S0w, "10");
    KS(17, rO, rE, S1r, S1w, "10");
    KS(18, rE, rO, S0r, S0w, "10");
    KS(19, rO, rE, S1r, S1w, "10");
    KS(20, rE, rO, S0r, S0w, "10");
    KS(21, rO, rE, S1r, S1w, "10");
    KS(22, rE, rO, S0r, S0w, "10");
    KS(23, rO, rE, S1r, S1w, "10");
    KS(24, rE, rO, S0r, S0w, "10");
    KS(25, rO, rE, S1r, S1w, "10");
    KS(26, rE, rO, S0r, S0w, "10");
    KS(27, rO, rE, S1r, S1w, "10");
    KS(28, rE, rO, S0r, S0w, "10");
    KS(29, rO, rE, S1r, S1w, "10");
    KS(30, rE, rO, S0r, S0w, "10");
    KS(31, rO, rE, S1r, S1w, "0");
#undef KS
#undef RAWLOAD

    // ---- epilogue: acc -> bf16 Cs[t][i][q] ----
    // (KS(31): vmcnt(0) drained all VMEM; ds_reads retired via MFMA
    //  consumption; final barrier synced -> Cs overlay safe)
    // C/D layout: col(c) = nt*16+l15, row(i) = w*16 + quad*4 + reg
    #pragma unroll
    for (int k = 0; k < 3; k++) {
        #pragma unroll
        for (int nt = 0; nt < 8; nt++) {
            int tl = nt >> 1;
            int q  = k * 32 + (nt & 1) * 16 + l15;
            #pragma unroll
            for (int reg = 0; reg < 4; reg++) {
                int il = w * 16 + quad * 4 + reg;
                Cs[(tl * 64 + il) * CS_LD + q] = f2bf(acc[k][nt][reg]);
            }
        }
    }
    __syncthreads();

    // ---- second GEMM: out[i][o] = relu( Cs[t][i][q] * ThetaT[o][q] ) ----
    bf16x8 bq[4][3];
    #pragma unroll
    for (int nt2 = 0; nt2 < 4; nt2++)
        #pragma unroll
        for (int kc = 0; kc < 3; kc++)
            bq[nt2][kc] = *(const bf16x8*)(Ts + (nt2 * 16 + l15) * TS_LD + kc * 32 + quad * 8);

    #pragma unroll
    for (int tl = 0; tl < 4; tl++) {
        bf16x8 af2[3];
        #pragma unroll
        for (int kc = 0; kc < 3; kc++)
            af2[kc] = *(const bf16x8*)(Cs + (size_t)(tl * 64 + w * 16 + l15) * CS_LD + kc * 32 + quad * 8);
        f32x4 acc2[4];
        #pragma unroll
        for (int nt2 = 0; nt2 < 4; nt2++)
            acc2[nt2] = (f32x4){0.f, 0.f, 0.f, 0.f};
        #pragma unroll
        for (int kc = 0; kc < 3; kc++)
            #pragma unroll
            for (int nt2 = 0; nt2 < 4; nt2++)
                acc2[nt2] = __builtin_amdgcn_mfma_f32_16x16x32_bf16(
                    af2[kc], bq[nt2][kc], acc2[nt2], 0, 0, 0);

        int tg = ct * 4 + tl;
        #pragma unroll
        for (int nt2 = 0; nt2 < 4; nt2++) {
            int o = nt2 * 16 + l15;
            #pragma unroll
            for (int reg = 0; reg < 4; reg++) {
                size_t row = (size_t)(b * T_ + tg) * N_ + i0 + w * 16 + quad * 4 + reg;
                out[row * 64 + o] = fmaxf(acc2[nt2][reg], 0.f);
            }
        }
    }
}

// ---------------------------------------------------------------------------
extern "C" void kernel_launch(void* const* d_in, const int* in_sizes, int n_in,
                              void* d_out, int out_size, void* d_ws, size_t ws_size,
                              hipStream_t stream) {
    const float* x     = (const float*)d_in[0];   // [B,T,N,FI]
    const float* att   = (const float*)d_in[1];   // [B,N,N]
    const float* cheb  = (const float*)d_in[2];   // [K,N,N]
    const float* theta = (const float*)d_in[3];   // [K,FI,FO]
    float* out = (float*)d_out;                   // [B,T,N,FO]

    // workspace: xt bf16 8.4 MB only (ac eliminated)
    unsigned short* xt = (unsigned short*)d_ws;

    prep<<<2048, 256, 0, stream>>>(x, xt);
    fused_gemm<<<512, 256, 0, stream>>>(att, cheb, xt, theta, out);
}

// Round 9
// 149.856 us; speedup vs baseline: 1.1654x; 1.1654x over previous
//
#include <hip/hip_runtime.h>
#include <hip/hip_bf16.h>

#define B_  8
#define T_  16
#define N_  1024
#define FI  32
#define FO  64
#define K_  3

typedef float  f32x4  __attribute__((ext_vector_type(4)));
typedef short  bf16x8 __attribute__((ext_vector_type(8)));
typedef unsigned int   u32x4 __attribute__((ext_vector_type(4)));

__device__ inline unsigned short f2bf(float f) {
    unsigned int u = __float_as_uint(f);
    u += 0x7fffu + ((u >> 16) & 1u);
    return (unsigned short)(u >> 16);
}

// packed fp32x2 -> bf16x2 (v_cvt_pk_bf16_f32 on gfx950)
__device__ inline unsigned int pkbf2(float a, float b) {
    __hip_bfloat162 h = __float22bfloat162_rn(make_float2(a, b));
    union { __hip_bfloat162 h2; unsigned int u; } cvt;
    cvt.h2 = h;
    return cvt.u;
}

// async 16-B global -> LDS (global_load_lds_dwordx4); LDS dest is
// wave-uniform base + lane*16 (contiguous per wave).
__device__ inline void gl_lds16(const unsigned short* g, unsigned short* l) {
    __builtin_amdgcn_global_load_lds(
        (const __attribute__((address_space(1))) unsigned int*)g,
        (__attribute__((address_space(3))) unsigned int*)l, 16, 0, 0);
}

// ---------------------------------------------------------------------------
// Kernel 1 "prep" (R0-proven form, reinstated after R8's on-the-fly A
// failure proved bf16 ac via prep is the cheaper A-path):
//   tasks 0..2047   : transpose x[b,t,j,f] fp32 -> xt[b, t*32+f, j] bf16
//   tasks 2048..6143: AC[b,k,ij] = cheb[k,ij]*att[b,ij] bf16 (b-parallel)
// ---------------------------------------------------------------------------
__global__ __launch_bounds__(256)
void prep(const float* __restrict__ x, const float* __restrict__ att,
          const float* __restrict__ cheb,
          unsigned short* __restrict__ xt, unsigned short* __restrict__ ac) {
    __shared__ __align__(16) float tile[64][33];
    int task = blockIdx.x;
    int tid  = threadIdx.x;

    if (task < 2048) {
        int jt = task & 15;
        int bt = task >> 4;
        int j0 = jt * 64;
        const float* src = x + (size_t)bt * (N_ * FI) + (size_t)j0 * FI;
        #pragma unroll
        for (int s = 0; s < 2; s++) {
            int e4 = tid + s * 256;
            int j  = e4 >> 3;
            int f4 = e4 & 7;
            f32x4 v = *(const f32x4*)(src + j * FI + f4 * 4);
            tile[j][f4 * 4 + 0] = v[0];
            tile[j][f4 * 4 + 1] = v[1];
            tile[j][f4 * 4 + 2] = v[2];
            tile[j][f4 * 4 + 3] = v[3];
        }
        __syncthreads();
        int f  = tid >> 3;
        int j8 = (tid & 7) * 8;
        u32x4 pk;
        #pragma unroll
        for (int u = 0; u < 4; u++)
            pk[u] = pkbf2(tile[j8 + 2 * u][f], tile[j8 + 2 * u + 1][f]);
        *(u32x4*)(xt + (size_t)bt * (32 * 1024) + j0 + f * 1024 + j8) = pk;
    } else {
        int e  = (task - 2048) * 256 + tid;   // 0..1048575
        int b  = e >> 17;
        size_t ij = (size_t)(e & 131071) * 8;
        const float* ap = att + (size_t)b * (N_ * N_) + ij;
        f32x4 a0 = ((const f32x4*)ap)[0];
        f32x4 a1 = ((const f32x4*)ap)[1];
        #pragma unroll
        for (int k = 0; k < K_; k++) {
            const float* cp = cheb + (size_t)k * (N_ * N_) + ij;
            f32x4 c0 = ((const f32x4*)cp)[0];
            f32x4 c1 = ((const f32x4*)cp)[1];
            u32x4 pk;
            pk[0] = pkbf2(c0[0] * a0[0], c0[1] * a0[1]);
            pk[1] = pkbf2(c0[2] * a0[2], c0[3] * a0[3]);
            pk[2] = pkbf2(c1[0] * a1[0], c1[1] * a1[1]);
            pk[3] = pkbf2(c1[2] * a1[2], c1[3] * a1[3]);
            *(u32x4*)(ac + (size_t)(b * K_ + k) * (N_ * N_) + ij) = pk;
        }
    }
}

// ---------------------------------------------------------------------------
// Kernel 2 (fused, v9): merge of R6 + R7's good halves.
//   BK=64 (R6): 16 ensembles x 48 MFMA -> half the barrier count of R7.
//   Triple-buffer (R7): stage(kb+2) never hits the buffer read at kb ->
//     ZERO lgkm drains (R6's flaw); compiler interleaves the 16 ds_reads
//     with the 48 MFMAs via its fine-grained lgkmcnt.
//   A even/odd direct-to-reg prefetch: cover is now a full BK=64 KS
//     (~2x R7) to hide the L3 latency (ac[b]=6.3MB > 4MB L2 -> L3 hits).
// Per KS(kb): [A(kb+1) 6 loads] [48 MFMA + 16 ds_read interleaved; the
// compiler's auto vmcnt(10) wait on A(kb) keeps stage(kb+1)+A(kb+1) in
// flight] [vmcnt(6): drains stage(kb+1), newer = A(kb+1)6] [s_barrier]
// [STAGE(kb+2)].  WAR: STAGE(kb+2) writes buf((kb-1)%3), whose reads
// retired before KS(kb-1)'s barrier.  Staging 3x16KB = 48 KB under the
// 53.2 KB Cs overlay -> LDS 66.5 KB, 2 blocks/CU.
// ---------------------------------------------------------------------------
#define TS_LD 104
#define CS_LD 104

__global__ __launch_bounds__(256, 2)
void fused_gemm(const unsigned short* __restrict__ ac,
                const unsigned short* __restrict__ xt,
                const float* __restrict__ theta,
                float* __restrict__ out) {
    // union: staging 3 x 8192 shorts (48 KB) lives under epilogue Cs
    // (4t x 64i x CS_LD = 26624 shorts = 53.2 KB).  + Ts 13.3 KB = 66.5 KB.
    __shared__ __align__(16) unsigned short ldsU[4 * 64 * CS_LD];
    __shared__ __align__(16) unsigned short Ts[FO * TS_LD];     // Theta^T

    unsigned short* Cs = ldsU;              // [4 t][64 i][CS_LD q]

    int blk  = blockIdx.x;
    int b    = blk & 7;          // XCD-aligned batch
    int slot = blk >> 3;         // 0..63
    int it   = slot >> 2;        // 0..15
    int ct   = slot & 3;         // 0..3
    int i0   = it * 64;
    int c0   = ct * 128;

    int tid  = threadIdx.x;
    int lane = tid & 63;
    int w    = tid >> 6;         // wave 0..3: owns i-rows w*16..w*16+15
    int quad = lane >> 4;
    int l15  = lane & 15;

    // stage Theta^T: Ts[o][q] = bf16(theta[q*64+o]), q = k*32+f
    #pragma unroll
    for (int s = 0; s < 24; s++) {
        int e = tid + s * 256;
        int q = e >> 6, o = e & 63;
        Ts[o * TS_LD + q] = f2bf(theta[e]);
    }
    // clean vmcnt slate before the counted region (theta loads were VMEM)
    asm volatile("s_waitcnt vmcnt(0)" ::: "memory");
    __builtin_amdgcn_sched_barrier(0);

    const unsigned short* Ag = ac + (size_t)b * (K_ * N_ * N_);
    const unsigned short* Bg = xt + (size_t)b * (512 * 1024);

    // ---- B staging addresses (3-bit source swizzle, LDS linear; R6) ----
    // LDS linear idx L = seg*2048 + tid*8 -> (row = seg*32 + tid/8,
    // sl = tid&7).  Source col slot = sl ^ (row&7) = (tid&7)^((tid>>3)&7).
    int srow = tid >> 3;                              // 0..31 within seg
    int scol = (((tid & 7) ^ (srow & 7)) * 8);        // swizzled source col
    const unsigned short* BrS0 = Bg + (size_t)(c0 + srow)      * N_ + scol;
    const unsigned short* BrS1 = Bg + (size_t)(c0 + srow + 32) * N_ + scol;
    const unsigned short* BrS2 = Bg + (size_t)(c0 + srow + 64) * N_ + scol;
    const unsigned short* BrS3 = Bg + (size_t)(c0 + srow + 96) * N_ + scol;
    unsigned short* R0 = ldsU;
    unsigned short* R1 = ldsU + 8192;
    unsigned short* R2 = ldsU + 16384;
    unsigned short* W0 = R0 + tid * 8;
    unsigned short* W1 = R1 + tid * 8;
    unsigned short* W2 = R2 + tid * 8;

    // read-side swizzle: logical slot s lives at LDS slot s ^ (row&7),
    // row = nt*16 + l15 -> row&7 = l15&7.
    int sw  = l15 & 7;
    int rd0 = l15 * 64 + ((quad ^ sw) * 8);           // k-half 0: slots 0..3
    int rd1 = l15 * 64 + (((4 + quad) ^ sw) * 8);     // k-half 1: slots 4..7

    // ---- A fragment pointers (direct global) ----
    const unsigned short* Af0 = Ag + (size_t)(i0 + w * 16 + l15) * N_ + quad * 8;
    const unsigned short* Af1 = Af0 + (size_t)N_ * N_;
    const unsigned short* Af2 = Af1 + (size_t)N_ * N_;

    f32x4 acc[3][8];
    #pragma unroll
    for (int k = 0; k < 3; k++)
        #pragma unroll
        for (int nt = 0; nt < 8; nt++)
            acc[k][nt] = (f32x4){0.f, 0.f, 0.f, 0.f};

    bf16x8 aE[3][2], aO[3][2];

#define STAGE(j, SW)                                                          \
    do {                                                                      \
        gl_lds16(BrS0 + (j) * 64, (SW));                                      \
        gl_lds16(BrS1 + (j) * 64, (SW) + 2048);                               \
        gl_lds16(BrS2 + (j) * 64, (SW) + 4096);                               \
        gl_lds16(BrS3 + (j) * 64, (SW) + 6144);                               \
    } while (0)

#define ALOAD(R, kb)                                                          \
    do {                                                                      \
        R[0][0] = *(const bf16x8*)(Af0 + (kb) * 64);                          \
        R[0][1] = *(const bf16x8*)(Af0 + (kb) * 64 + 32);                     \
        R[1][0] = *(const bf16x8*)(Af1 + (kb) * 64);                          \
        R[1][1] = *(const bf16x8*)(Af1 + (kb) * 64 + 32);                     \
        R[2][0] = *(const bf16x8*)(Af2 + (kb) * 64);                          \
        R[2][1] = *(const bf16x8*)(Af2 + (kb) * 64 + 32);                     \
    } while (0)

    // ---- prologue: stage0(4), A0(6), stage1(4) -- order pinned ----
    STAGE(0, W0);
    __builtin_amdgcn_sched_barrier(0);
    ALOAD(aE, 0);
    __builtin_amdgcn_sched_barrier(0);
    STAGE(1, W1);
    // drain stage(0): newer = A(0)6 + stage(1)4 = 10
    asm volatile("s_waitcnt vmcnt(10)" ::: "memory");
    __builtin_amdgcn_s_barrier();
    __builtin_amdgcn_sched_barrier(0);

#define KS(kb, Ac, An, SR, SW, WN)                                            \
  do {                                                                        \
    if ((kb) < 15) ALOAD(An, (kb) + 1);                                       \
    __builtin_amdgcn_s_setprio(1);                                            \
    {                                                                         \
      bf16x8 b0[8];                                                           \
      _Pragma("unroll")                                                       \
      for (int nt = 0; nt < 8; nt++)                                          \
        b0[nt] = *(const bf16x8*)((SR) + nt * 1024 + rd0);                    \
      _Pragma("unroll")                                                       \
      for (int nt = 0; nt < 8; nt++) {                                        \
        acc[0][nt] = __builtin_amdgcn_mfma_f32_16x16x32_bf16(Ac[0][0], b0[nt], acc[0][nt], 0, 0, 0); \
        acc[1][nt] = __builtin_amdgcn_mfma_f32_16x16x32_bf16(Ac[1][0], b0[nt], acc[1][nt], 0, 0, 0); \
        acc[2][nt] = __builtin_amdgcn_mfma_f32_16x16x32_bf16(Ac[2][0], b0[nt], acc[2][nt], 0, 0, 0); \
      }                                                                       \
    }                                                                         \
    {                                                                         \
      bf16x8 b1[8];                                                           \
      _Pragma("unroll")                                                       \
      for (int nt = 0; nt < 8; nt++)                                          \
        b1[nt] = *(const bf16x8*)((SR) + nt * 1024 + rd1);                    \
      _Pragma("unroll")                                                       \
      for (int nt = 0; nt < 8; nt++) {                                        \
        acc[0][nt] = __builtin_amdgcn_mfma_f32_16x16x32_bf16(Ac[0][1], b1[nt], acc[0][nt], 0, 0, 0); \
        acc[1][nt] = __builtin_amdgcn_mfma_f32_16x16x32_bf16(Ac[1][1], b1[nt], acc[1][nt], 0, 0, 0); \
        acc[2][nt] = __builtin_amdgcn_mfma_f32_16x16x32_bf16(Ac[2][1], b1[nt], acc[2][nt], 0, 0, 0); \
      }                                                                       \
    }                                                                         \
    __builtin_amdgcn_s_setprio(0);                                            \
    asm volatile("s_waitcnt vmcnt(" WN ")" ::: "memory");                     \
    __builtin_amdgcn_s_barrier();                                             \
    __builtin_amdgcn_sched_barrier(0);                                        \
    if ((kb) < 14)                                                            \
      STAGE((kb) + 2, SW);                                                    \
  } while (0)

    KS(0,  aE, aO, R0, W2, "6");
    KS(1,  aO, aE, R1, W0, "6");
    KS(2,  aE, aO, R2, W1, "6");
    KS(3,  aO, aE, R0, W2, "6");
    KS(4,  aE, aO, R1, W0, "6");
    KS(5,  aO, aE, R2, W1, "6");
    KS(6,  aE, aO, R0, W2, "6");
    KS(7,  aO, aE, R1, W0, "6");
    KS(8,  aE, aO, R2, W1, "6");
    KS(9,  aO, aE, R0, W2, "6");
    KS(10, aE, aO, R1, W0, "6");
    KS(11, aO, aE, R2, W1, "6");
    KS(12, aE, aO, R0, W2, "6");
    KS(13, aO, aE, R1, W0, "6");
    KS(14, aE, aO, R2, W0, "6");
    KS(15, aO, aE, R0, W0, "0");
#undef KS
#undef ALOAD
#undef STAGE

    // ---- epilogue: acc -> bf16 Cs[t][i][q] ----
    // (KS(15): vmcnt(0) drained all VMEM; ds_reads retired via MFMA
    //  consumption; final barrier synced -> Cs overlay safe)
    // C/D layout: col(c) = nt*16+l15, row(i) = w*16 + quad*4 + reg
    // t_loc = nt>>1 (l15 < 16 so it never crosses), f = (nt&1)*16 + l15
    #pragma unroll
    for (int k = 0; k < 3; k++) {
        #pragma unroll
        for (int nt = 0; nt < 8; nt++) {
            int tl = nt >> 1;
            int q  = k * 32 + (nt & 1) * 16 + l15;
            #pragma unroll
            for (int reg = 0; reg < 4; reg++) {
                int il = w * 16 + quad * 4 + reg;
                Cs[(tl * 64 + il) * CS_LD + q] = f2bf(acc[k][nt][reg]);
            }
        }
    }
    __syncthreads();

    // ---- second GEMM: out[i][o] = relu( Cs[t][i][q] * ThetaT[o][q] ) ----
    bf16x8 bq[4][3];
    #pragma unroll
    for (int nt2 = 0; nt2 < 4; nt2++)
        #pragma unroll
        for (int kc = 0; kc < 3; kc++)
            bq[nt2][kc] = *(const bf16x8*)(Ts + (nt2 * 16 + l15) * TS_LD + kc * 32 + quad * 8);

    #pragma unroll
    for (int tl = 0; tl < 4; tl++) {
        bf16x8 af2[3];
        #pragma unroll
        for (int kc = 0; kc < 3; kc++)
            af2[kc] = *(const bf16x8*)(Cs + (size_t)(tl * 64 + w * 16 + l15) * CS_LD + kc * 32 + quad * 8);
        f32x4 acc2[4];
        #pragma unroll
        for (int nt2 = 0; nt2 < 4; nt2++)
            acc2[nt2] = (f32x4){0.f, 0.f, 0.f, 0.f};
        #pragma unroll
        for (int kc = 0; kc < 3; kc++)
            #pragma unroll
            for (int nt2 = 0; nt2 < 4; nt2++)
                acc2[nt2] = __builtin_amdgcn_mfma_f32_16x16x32_bf16(
                    af2[kc], bq[nt2][kc], acc2[nt2], 0, 0, 0);

        int tg = ct * 4 + tl;
        #pragma unroll
        for (int nt2 = 0; nt2 < 4; nt2++) {
            int o = nt2 * 16 + l15;
            #pragma unroll
            for (int reg = 0; reg < 4; reg++) {
                size_t row = (size_t)(b * T_ + tg) * N_ + i0 + w * 16 + quad * 4 + reg;
                out[row * 64 + o] = fmaxf(acc2[nt2][reg], 0.f);
            }
        }
    }
}

// ---------------------------------------------------------------------------
extern "C" void kernel_launch(void* const* d_in, const int* in_sizes, int n_in,
                              void* d_out, int out_size, void* d_ws, size_t ws_size,
                              hipStream_t stream) {
    const float* x     = (const float*)d_in[0];   // [B,T,N,FI]
    const float* att   = (const float*)d_in[1];   // [B,N,N]
    const float* cheb  = (const float*)d_in[2];   // [K,N,N]
    const float* theta = (const float*)d_in[3];   // [K,FI,FO]
    float* out = (float*)d_out;                   // [B,T,N,FO]

    // workspace: xt bf16 8.4 MB | ac bf16 50.3 MB
    unsigned short* xt = (unsigned short*)d_ws;
    unsigned short* ac = xt + (size_t)B_ * 512 * 1024;

    prep<<<2048 + 4096, 256, 0, stream>>>(x, att, cheb, xt, ac);
    fused_gemm<<<512, 256, 0, stream>>>(ac, xt, theta, out);
}